// Round 9
// baseline (153.997 us; speedup 1.0000x reference)
//
#include <hip/hip_runtime.h>

#define D_FEAT 128
#define WAVE 64

typedef float nfloat4 __attribute__((ext_vector_type(4)));  // native vec for nt-store

__device__ __forceinline__ unsigned short f32_to_bf16_rn(float f) {
    unsigned int u = __float_as_uint(f);
    unsigned int r = u + 0x7fffu + ((u >> 16) & 1u);   // round-to-nearest-even
    return (unsigned short)(r >> 16);
}

// Fused pre-pass: blocks [0, grid_c) convert fp32->bf16 table (8 elems/thread,
// plus appended zero row at index n_nodes); blocks [grid_c, grid_c+grid_b)
// build CSR row offsets from the sorted row_ids.
__global__ void prep_kernel(const float* __restrict__ feats,
                            unsigned short* __restrict__ tbl,
                            int n_elems, int total,
                            const int* __restrict__ rids,
                            int* __restrict__ row_start,
                            int n_edges, int n_rows, int grid_c) {
    if ((int)blockIdx.x < grid_c) {
        int i = (blockIdx.x * blockDim.x + threadIdx.x) * 8;
        if (i >= total) return;
        if (i + 8 <= n_elems) {
            float4 a = *(const float4*)(feats + i);
            float4 b = *(const float4*)(feats + i + 4);
            uint4 o;
            o.x = (unsigned)f32_to_bf16_rn(a.x) | ((unsigned)f32_to_bf16_rn(a.y) << 16);
            o.y = (unsigned)f32_to_bf16_rn(a.z) | ((unsigned)f32_to_bf16_rn(a.w) << 16);
            o.z = (unsigned)f32_to_bf16_rn(b.x) | ((unsigned)f32_to_bf16_rn(b.y) << 16);
            o.w = (unsigned)f32_to_bf16_rn(b.z) | ((unsigned)f32_to_bf16_rn(b.w) << 16);
            *(uint4*)(tbl + i) = o;
        } else {
            for (int k = 0; k < 8 && i + k < total; ++k)
                tbl[i + k] = (i + k < n_elems) ? f32_to_bf16_rn(feats[i + k])
                                               : (unsigned short)0;
        }
    } else {
        int e = (blockIdx.x - grid_c) * blockDim.x + threadIdx.x;
        if (e >= n_edges) return;
        int r_cur  = rids[e];
        int r_prev = (e == 0) ? -1 : rids[e - 1];
        for (int r = r_prev + 1; r <= r_cur; ++r) row_start[r] = e;
        if (e == n_edges - 1) {
            for (int r = r_cur + 1; r <= n_rows; ++r) row_start[r] = n_edges;
        }
    }
}

// One wave per output row. bf16 row = 256 B -> quarter-wave (16 lanes x 16 B)
// per edge; one wave64 load gathers FOUR rows. Ids via one wave load + __shfl.
// Output stores and nid loads are NON-TEMPORAL (no reuse) so they don't
// write-allocate in L2 and evict table lines; table gathers stay cached
// (measured 59% L2 hit). float2 accumulators -> v_pk_add_f32.
__global__ void __launch_bounds__(256)
mean_agg_kernel(const uint4* __restrict__ tbl4,
                const int* __restrict__ nids,
                const int* __restrict__ row_start,
                float* __restrict__ out,
                int n_rows, int zero_row) {
    int wave = (blockIdx.x * blockDim.x + threadIdx.x) >> 6;
    int lane = threadIdx.x & (WAVE - 1);
    if (wave >= n_rows) return;

    const int q   = lane >> 4;     // quarter 0..3 -> which edge of a group of 4
    const int sub = lane & 15;     // uint4 slot within the 256 B row

    int lo = row_start[wave];
    int hi = row_start[wave + 1];

    float2 acc[4];
    #pragma unroll
    for (int k = 0; k < 4; ++k) acc[k] = make_float2(0.f, 0.f);

    int e = lo;
    // full loop: 32 edges, ids via one nt wave load + shuffle, 8 gathers in flight
    for (; e + 32 <= hi; e += 32) {
        int myid = __builtin_nontemporal_load(nids + e + (lane & 31));
        uint4 u[8];
        #pragma unroll
        for (int g = 0; g < 8; ++g) {
            int nid = __shfl(myid, 4 * g + q, WAVE);
            u[g] = tbl4[((unsigned)nid << 4) + (unsigned)sub];
        }
        #pragma unroll
        for (int g = 0; g < 8; ++g) {
            acc[0].x += __uint_as_float(u[g].x << 16);
            acc[0].y += __uint_as_float(u[g].x & 0xffff0000u);
            acc[1].x += __uint_as_float(u[g].y << 16);
            acc[1].y += __uint_as_float(u[g].y & 0xffff0000u);
            acc[2].x += __uint_as_float(u[g].z << 16);
            acc[2].y += __uint_as_float(u[g].z & 0xffff0000u);
            acc[3].x += __uint_as_float(u[g].w << 16);
            acc[3].y += __uint_as_float(u[g].w & 0xffff0000u);
        }
    }
    // remainder: up to 2 clamped step-16 blocks (wave-uniform branches)
    #pragma unroll
    for (int half_blk = 0; half_blk < 2; ++half_blk) {
        if (e < hi) {
            #pragma unroll
            for (int g = 0; g < 4; ++g) {
                int idx = e + 4 * g + q;
                int idc = idx < hi ? idx : hi - 1;
                int nid = nids[idc];
                nid = idx < hi ? nid : zero_row;
                uint4 u = tbl4[((unsigned)nid << 4) + (unsigned)sub];
                acc[0].x += __uint_as_float(u.x << 16);
                acc[0].y += __uint_as_float(u.x & 0xffff0000u);
                acc[1].x += __uint_as_float(u.y << 16);
                acc[1].y += __uint_as_float(u.y & 0xffff0000u);
                acc[2].x += __uint_as_float(u.z << 16);
                acc[2].y += __uint_as_float(u.z & 0xffff0000u);
                acc[3].x += __uint_as_float(u.w << 16);
                acc[3].y += __uint_as_float(u.w & 0xffff0000u);
            }
            e += 16;
        }
    }

    // fold the four quarter-wave accumulators (xor 16, then 32)
    #pragma unroll
    for (int k = 0; k < 4; ++k) {
        acc[k].x += __shfl_xor(acc[k].x, 16, WAVE);
        acc[k].y += __shfl_xor(acc[k].y, 16, WAVE);
        acc[k].x += __shfl_xor(acc[k].x, 32, WAVE);
        acc[k].y += __shfl_xor(acc[k].y, 32, WAVE);
    }

    int deg = hi - lo;
    float inv = 1.0f / (float)(deg > 0 ? deg : 1);

    // lanes 0-31 each store one float4 (non-temporal) -> coalesced 512 B row
    if (q < 2) {
        nfloat4 o;
        o.x = (q == 0 ? acc[0].x : acc[2].x) * inv;
        o.y = (q == 0 ? acc[0].y : acc[2].y) * inv;
        o.z = (q == 0 ? acc[1].x : acc[3].x) * inv;
        o.w = (q == 0 ? acc[1].y : acc[3].y) * inv;
        __builtin_nontemporal_store(o, (nfloat4*)(out + (size_t)wave * D_FEAT + sub * 8 + q * 4));
    }
}

extern "C" void kernel_launch(void* const* d_in, const int* in_sizes, int n_in,
                              void* d_out, int out_size, void* d_ws, size_t ws_size,
                              hipStream_t stream) {
    const float* feats = (const float*)d_in[0];
    const int* nids    = (const int*)d_in[1];
    const int* rids    = (const int*)d_in[2];
    float* out         = (float*)d_out;

    int n_feat_elems = in_sizes[0];
    int n_nodes      = n_feat_elems / D_FEAT;
    int n_edges      = in_sizes[1];
    int n_rows       = out_size / D_FEAT;

    // ws layout: [bf16 table, (n_nodes+1) rows incl. zero row][row_start]
    unsigned short* tbl = (unsigned short*)d_ws;
    size_t tbl_bytes = (size_t)(n_nodes + 1) * D_FEAT * sizeof(unsigned short);
    tbl_bytes = (tbl_bytes + 255) & ~(size_t)255;
    int* row_start = (int*)((char*)d_ws + tbl_bytes);

    const int BLOCK = 256;

    int total_tbl = (n_nodes + 1) * D_FEAT;
    int grid_c = ((total_tbl + 7) / 8 + BLOCK - 1) / BLOCK;
    int grid_b = (n_edges + BLOCK - 1) / BLOCK;
    prep_kernel<<<grid_c + grid_b, BLOCK, 0, stream>>>(feats, tbl, n_feat_elems,
                                                       total_tbl, rids, row_start,
                                                       n_edges, n_rows, grid_c);

    int waves_per_block = BLOCK / WAVE;
    int grid_a = (n_rows + waves_per_block - 1) / waves_per_block;
    mean_agg_kernel<<<grid_a, BLOCK, 0, stream>>>((const uint4*)tbl, nids, row_start,
                                                  out, n_rows, n_nodes);
}